// Round 5
// baseline (210.927 us; speedup 1.0000x reference)
//
#include <hip/hip_runtime.h>
#include <math.h>

// z:  (2,1,256,256,64)  idx = b*4194304 + x*16384 + y*64 + k
// tg: (2,3,256,256,64)  idx = b*12582912 + c*4194304 + x*16384 + y*64 + k
//
// No LDS staging: thread = (cell, k-quad) in a 4x4-cell tile, all data loaded
// directly from global (L1/L2 serve the 4-6x neighbor reuse). k+1 shift is a
// +4B offset inside the thread's own dwordx4 loads — no shuffles, no barriers.
// Div accumulation is field-by-field (bx, by, bz) to cap register liveness.
//
// ws layout (floats), 32 slices x 258:
//   sl[p*258 + 0]=smooth, +1=div, +2+b*64+k = s1, +130+b*64+k = s2

__global__ __launch_bounds__(512) void zero_ws_kernel(float* ws) {
    for (int i = threadIdx.x; i < 32 * 258; i += 512) ws[i] = 0.0f;
}

__device__ __forceinline__ void ld5(float* a, const float* p, int d4) {
    float4 x = *(const float4*)p;
    float4 y = *(const float4*)(p + d4);
    a[0] = x.x; a[1] = x.y; a[2] = x.z; a[3] = x.w; a[4] = y.x;
}

__global__ __launch_bounds__(256, 4) void fused_loss_kernel(
    const float* __restrict__ zin, const float* __restrict__ tg,
    float* __restrict__ ws)
{
    __shared__ float r1[1024];
    __shared__ float r2[1024];
    __shared__ float rsc[4][2];

    const int tid  = threadIdx.x;
    const int lane = tid & 63;
    const int w    = tid >> 6;

    const int bb   = blockIdx.x >> 12;
    const int rest = blockIdx.x & 4095;
    const int x0 = ((rest >> 6) & 63) << 2;
    const int y0 = (rest & 63) << 2;

    const int c  = tid >> 4;
    const int kq = tid & 15;
    const int cx = c & 3, cy = c >> 2;
    const int xg = x0 + cx, yg = y0 + cy;
    const int k0 = kq << 2;
    const int d4 = (kq < 15) ? 4 : 0;       // clamp second float4 at k-edge

    const int xE = (xg < 255) ? xg + 1 : 255;
    const int xW = (xg > 0)   ? xg - 1 : 0;
    const int yN = (yg < 255) ? yg + 1 : 255;
    const int yS = (yg > 0)   ? yg - 1 : 0;

    const int oC  = xg * 16384 + yg * 64 + k0;
    const int oE  = xE * 16384 + yg * 64 + k0;
    const int oW  = xW * 16384 + yg * 64 + k0;
    const int oN  = xg * 16384 + yN * 64 + k0;
    const int oS  = xg * 16384 + yS * 64 + k0;
    const int oNE = xE * 16384 + yN * 64 + k0;

    const float* zg = zin + ((size_t)bb << 22);

    // ---- z loads ----
    float zcv[7];
    {
        int km = (k0 >= 4) ? -4 : 0;
        float4 m = *(const float4*)&zg[oC + km];
        float4 a = *(const float4*)&zg[oC];
        float4 b = *(const float4*)&zg[oC + d4];
        zcv[0] = m.w; zcv[1] = a.x; zcv[2] = a.y; zcv[3] = a.z; zcv[4] = a.w;
        zcv[5] = b.x; zcv[6] = b.y;
    }
    float zEv[5], zWv[5], zNv[5], zSv[5], zNEv[5];
    ld5(zEv,  &zg[oE],  d4);
    ld5(zWv,  &zg[oW],  d4);
    ld5(zNv,  &zg[oN],  d4);
    ld5(zSv,  &zg[oS],  d4);
    ld5(zNEv, &zg[oNE], d4);

    // ---- dz + std partials ----
    float dz0[4], dzE[4], dzN[4], dzNE[4];
    #pragma unroll
    for (int e = 0; e < 4; ++e) {
        dz0[e]  = zcv[e + 2] - zcv[e + 1];
        dzE[e]  = zEv[e + 1] - zEv[e];
        dzN[e]  = zNv[e + 1] - zNv[e];
        dzNE[e] = zNEv[e + 1] - zNEv[e];
    }
    float s1a[4], s2a[4];
    #pragma unroll
    for (int e = 0; e < 4; ++e) {
        bool kok = (k0 + e) < 63;
        s1a[e] = kok ? dz0[e] : 0.0f;
        s2a[e] = kok ? dz0[e] * dz0[e] : 0.0f;
    }

    // ---- smooth ----
    float sm = 0.0f;
    if (xg >= 1 && xg <= 254 && yg >= 1 && yg <= 254) {
        #pragma unroll
        for (int e = 0; e < 4; ++e) {
            int k = k0 + e;
            if (k >= 1 && k <= 61) {
                float dzm = zcv[e + 1] - zcv[e];
                float dzp = zcv[e + 3] - zcv[e + 2];
                float dzw = zWv[e + 1] - zWv[e];
                float dzs = zSv[e + 1] - zSv[e];
                float lap = 6.0f * dz0[e] * dz0[e]
                          - dzw * dzw - dzE[e] * dzE[e]
                          - dzs * dzs - dzN[e] * dzN[e]
                          - dzm * dzm - dzp * dzp;
                sm += lap * lap;
            }
        }
    }

    // ---- div: z corner diffs, then per-field accumulation ----
    float dv = 0.0f;
    if (xg < 255 && yg < 255) {
        float dCE[5], dCN[5], dENE[5], dNNE[5];
        #pragma unroll
        for (int j = 0; j < 5; ++j) {
            dCE[j]  = zcv[j + 1] - zEv[j];
            dCN[j]  = zcv[j + 1] - zNv[j];
            dENE[j] = zEv[j] - zNEv[j];
            dNNE[j] = zNv[j] - zNEv[j];
        }
        float adz00[4], adz10[4], adz01[4], adz11[4];
        #pragma unroll
        for (int e = 0; e < 4; ++e) {
            adz00[e] = fabsf(dz0[e]);  adz10[e] = fabsf(dzE[e]);
            adz01[e] = fabsf(dzN[e]);  adz11[e] = fabsf(dzNE[e]);
        }

        const int p00 = oC, p10 = oE, p01 = oN, p11 = oNE;
        const float* bxg = tg + ((size_t)(bb * 3) << 22);
        const float* byg = bxg + (1u << 22);
        const float* bzg = byg + (1u << 22);
        const float c6 = 1.0f / 6.0f;

        float num[4], den[4];

        // -- bx --
        {
            float a00[5], a10[5], a01[5], a11[5];
            ld5(a00, &bxg[p00], d4);  ld5(a10, &bxg[p10], d4);
            ld5(a01, &bxg[p01], d4);  ld5(a11, &bxg[p11], d4);
            #pragma unroll
            for (int e = 0; e < 4; ++e) {
                float s10 = a10[e] + a10[e + 1] + a11[e] + a11[e + 1];
                float s00 = a00[e] + a00[e + 1] + a01[e] + a01[e + 1];
                num[e] = 0.125f * (s10 * (adz10[e] + adz11[e])
                                 - s00 * (adz00[e] + adz01[e]));
                num[e] += c6 * ( (a00[e + 1] + a10[e + 1] + a11[e + 1]) * dCE[e + 1]
                               + (a01[e + 1] + a11[e + 1] + a10[e + 1]) * dNNE[e + 1]
                               - (a00[e] + a10[e] + a11[e]) * dCE[e]
                               - (a01[e] + a11[e] + a10[e]) * dNNE[e] );
                float sbx = s10 + s00;
                den[e] = sbx * sbx;
            }
        }
        // -- by --
        {
            float a00[5], a10[5], a01[5], a11[5];
            ld5(a00, &byg[p00], d4);  ld5(a10, &byg[p10], d4);
            ld5(a01, &byg[p01], d4);  ld5(a11, &byg[p11], d4);
            #pragma unroll
            for (int e = 0; e < 4; ++e) {
                float s01 = a01[e] + a01[e + 1] + a11[e] + a11[e + 1];
                float s00 = a00[e] + a00[e + 1] + a10[e] + a10[e + 1];
                num[e] += 0.125f * (s01 * (adz01[e] + adz11[e])
                                  - s00 * (adz00[e] + adz10[e]));
                num[e] += c6 * ( (a10[e + 1] + a11[e + 1] + a01[e + 1]) * dENE[e + 1]
                               + (a00[e + 1] + a01[e + 1] + a11[e + 1]) * dCN[e + 1]
                               - (a10[e] + a11[e] + a01[e]) * dENE[e]
                               - (a00[e] + a01[e] + a11[e]) * dCN[e] );
                float sby = s01 + s00;
                den[e] += sby * sby;
            }
        }
        // -- bz --
        {
            float a00[5], a10[5], a01[5], a11[5];
            ld5(a00, &bzg[p00], d4);  ld5(a10, &bzg[p10], d4);
            ld5(a01, &bzg[p01], d4);  ld5(a11, &bzg[p11], d4);
            #pragma unroll
            for (int e = 0; e < 4; ++e) {
                float slo = a00[e] + a10[e] + a01[e] + a11[e];
                float shi = a00[e + 1] + a10[e + 1] + a01[e + 1] + a11[e + 1];
                num[e] += 0.25f * (shi - slo);
                float sbz = slo + shi;
                den[e] += sbz * sbz;
            }
        }
        #pragma unroll
        for (int e = 0; e < 4; ++e) {
            if ((k0 + e) < 63) {
                float d = den[e] * 0.015625f + 1e-10f;
                dv += num[e] * num[e] * __builtin_amdgcn_rcpf(d);
            }
        }
    }

    // ---- block reduction ----
    #pragma unroll
    for (int off = 32; off > 0; off >>= 1) {
        sm += __shfl_down(sm, off, 64);
        dv += __shfl_down(dv, off, 64);
    }

    { float4 v; v.x = s1a[0]; v.y = s1a[1]; v.z = s1a[2]; v.w = s1a[3];
      *(float4*)&r1[tid << 2] = v; }
    { float4 v; v.x = s2a[0]; v.y = s2a[1]; v.z = s2a[2]; v.w = s2a[3];
      *(float4*)&r2[tid << 2] = v; }
    if (lane == 0) { rsc[w][0] = sm; rsc[w][1] = dv; }
    __syncthreads();

    if (tid < 64) {
        float a = 0.0f, b2 = 0.0f;
        #pragma unroll
        for (int cc = 0; cc < 16; ++cc) {
            a  += r1[cc * 64 + tid];
            b2 += r2[cc * 64 + tid];
        }
        float* sl = ws + (blockIdx.x & 31) * 258;
        if (tid < 63) {
            atomicAdd(&sl[2 + bb * 64 + tid],   a);
            atomicAdd(&sl[130 + bb * 64 + tid], b2);
        }
        if (tid == 0) atomicAdd(&sl[0], rsc[0][0] + rsc[1][0] + rsc[2][0] + rsc[3][0]);
        if (tid == 1) atomicAdd(&sl[1], rsc[0][1] + rsc[1][1] + rsc[2][1] + rsc[3][1]);
    }
}

__global__ __launch_bounds__(128) void finalize_kernel(const float* __restrict__ ws,
                                                       float* __restrict__ out)
{
    __shared__ double red[128];
    const int t = threadIdx.x;
    double stdv = 0.0;
    {
        int k = t & 63, bb = t >> 6;
        if (k < 63) {
            double s1 = 0.0, s2 = 0.0;
            for (int p = 0; p < 32; ++p) {
                s1 += (double)ws[p * 258 + 2 + bb * 64 + k];
                s2 += (double)ws[p * 258 + 130 + bb * 64 + k];
            }
            const double N = 65536.0;
            double var = (s2 - s1 * s1 / N) / (N - 1.0);
            stdv = sqrt(var > 0.0 ? var : 0.0);
        }
    }
    red[t] = stdv;
    __syncthreads();
    for (int off = 64; off > 0; off >>= 1) {
        if (t < off) red[t] += red[t + off];
        __syncthreads();
    }
    if (t == 0) {
        double smt = 0.0, dvt = 0.0;
        for (int p = 0; p < 32; ++p) {
            smt += (double)ws[p * 258 + 0];
            dvt += (double)ws[p * 258 + 1];
        }
        double loss_std    = red[0] / 126.0;
        double loss_smooth = smt / (2.0 * 254.0 * 254.0 * 61.0);
        double loss_div    = dvt / (2.0 * 255.0 * 255.0 * 63.0);
        out[0] = (float)(loss_div * 1e9);
        out[1] = (float)(loss_smooth * 10.0 + loss_std * 100.0);
    }
}

extern "C" void kernel_launch(void* const* d_in, const int* in_sizes, int n_in,
                              void* d_out, int out_size, void* d_ws, size_t ws_size,
                              hipStream_t stream) {
    const float* z  = (const float*)d_in[0];   // outputs (2,1,256,256,64)
    const float* tg = (const float*)d_in[1];   // targets (2,3,256,256,64)
    float* out = (float*)d_out;
    float* ws  = (float*)d_ws;

    zero_ws_kernel<<<1, 512, 0, stream>>>(ws);
    // 64x64 tiles x 2 batches = 8192 blocks
    fused_loss_kernel<<<8192, 256, 0, stream>>>(z, tg, ws);
    finalize_kernel<<<1, 128, 0, stream>>>(ws, out);
}

// Round 6
// 206.944 us; speedup vs baseline: 1.0192x; 1.0192x over previous
//
#include <hip/hip_runtime.h>
#include <math.h>

// z:  (2,1,256,256,64)  idx = b*4194304 + x*16384 + y*64 + k
// tg: (2,3,256,256,64)  idx = b*12582912 + c*4194304 + x*16384 + y*64 + k
//
// Hybrid: b fields (bx,by,bz) staged in LDS (19.4 KB -> 8 blocks/CU; buffer
// reused for the final reduction). z read directly from global (L1/L2 serve
// the 6x neighbor reuse; XCD swizzle keeps x-adjacent tiles on one XCD's L2).
// Thread = (cell, k-quad) in a 4x4-cell tile; k+1 shift = +4B in-register.
//
// ws layout (floats), 32 slices x 258:
//   sl[p*258 + 0]=smooth, +1=div, +2+b*64+k = s1, +130+b*64+k = s2

#define BSTR 324            // 5 rows * 64 + 4 pad (floats), 16B-aligned
#define BFLD 1620           // 5 strips * BSTR

__global__ __launch_bounds__(512) void zero_ws_kernel(float* ws) {
    for (int i = threadIdx.x; i < 32 * 258; i += 512) ws[i] = 0.0f;
}

__device__ __forceinline__ void ld5(float* a, const float* p, int d4) {
    float4 x = *(const float4*)p;
    float4 y = *(const float4*)(p + d4);
    a[0] = x.x; a[1] = x.y; a[2] = x.z; a[3] = x.w; a[4] = y.x;
}

__global__ __launch_bounds__(256, 4) void fused_loss_kernel(
    const float* __restrict__ zin, const float* __restrict__ tg,
    float* __restrict__ ws)
{
    __shared__ float bs[3 * BFLD];       // 4860 floats = 19.44 KB
    __shared__ float rsc[4][2];

    const int tid  = threadIdx.x;
    const int lane = tid & 63;
    const int w    = tid >> 6;

    // XCD swizzle: blocks i, i+8, i+16... share an XCD; give each XCD a
    // contiguous range of tiles so x/y-neighbor halos hit its L2.
    const int virt = ((blockIdx.x & 7) << 10) | (blockIdx.x >> 3);
    const int bb   = virt >> 12;
    const int rest = virt & 4095;
    const int x0 = ((rest >> 6) & 63) << 2;
    const int y0 = (rest & 63) << 2;

    // ---- stage b fields: 3 fields x 5x5 rows x 16 float4 = 1200 float4 ----
    for (int i = tid; i < 1200; i += 256) {
        int f  = i / 400;
        int jj = i - f * 400;
        int row = jj >> 4;
        int o   = (jj & 15) << 2;
        int xi  = row / 5;
        int yr  = row - xi * 5;
        int x = x0 + xi; x = x > 255 ? 255 : x;
        int y = y0 + yr; y = y > 255 ? 255 : y;
        const float* g = tg + ((size_t)(bb * 3 + f) << 22);
        *(float4*)&bs[f * BFLD + xi * BSTR + yr * 64 + o] =
            *(const float4*)&g[x * 16384 + y * 64 + o];
    }

    const int c  = tid >> 4;
    const int kq = tid & 15;
    const int cx = c & 3, cy = c >> 2;
    const int xg = x0 + cx, yg = y0 + cy;
    const int k0 = kq << 2;
    const int d4 = (kq < 15) ? 4 : 0;       // clamp second float4 at k-edge

    const int xE = (xg < 255) ? xg + 1 : 255;
    const int xW = (xg > 0)   ? xg - 1 : 0;
    const int yN = (yg < 255) ? yg + 1 : 255;
    const int yS = (yg > 0)   ? yg - 1 : 0;

    const int oC  = xg * 16384 + yg * 64 + k0;
    const int oE  = xE * 16384 + yg * 64 + k0;
    const int oW  = xW * 16384 + yg * 64 + k0;
    const int oN  = xg * 16384 + yN * 64 + k0;
    const int oS  = xg * 16384 + yS * 64 + k0;
    const int oNE = xE * 16384 + yN * 64 + k0;

    const float* zg = zin + ((size_t)bb << 22);

    // ---- z loads (global, overlap with staging; barrier comes after) ----
    float zcv[7];
    {
        int km = (k0 >= 4) ? -4 : 0;
        float4 m = *(const float4*)&zg[oC + km];
        float4 a = *(const float4*)&zg[oC];
        float4 b = *(const float4*)&zg[oC + d4];
        zcv[0] = m.w; zcv[1] = a.x; zcv[2] = a.y; zcv[3] = a.z; zcv[4] = a.w;
        zcv[5] = b.x; zcv[6] = b.y;
    }
    float zEv[5], zWv[5], zNv[5], zSv[5], zNEv[5];
    ld5(zEv,  &zg[oE],  d4);
    ld5(zWv,  &zg[oW],  d4);
    ld5(zNv,  &zg[oN],  d4);
    ld5(zSv,  &zg[oS],  d4);
    ld5(zNEv, &zg[oNE], d4);

    // ---- dz + std partials ----
    float dz0[4], dzE[4], dzN[4], dzNE[4];
    #pragma unroll
    for (int e = 0; e < 4; ++e) {
        dz0[e]  = zcv[e + 2] - zcv[e + 1];
        dzE[e]  = zEv[e + 1] - zEv[e];
        dzN[e]  = zNv[e + 1] - zNv[e];
        dzNE[e] = zNEv[e + 1] - zNEv[e];
    }
    float s1a[4], s2a[4];
    #pragma unroll
    for (int e = 0; e < 4; ++e) {
        bool kok = (k0 + e) < 63;
        s1a[e] = kok ? dz0[e] : 0.0f;
        s2a[e] = kok ? dz0[e] * dz0[e] : 0.0f;
    }

    // ---- smooth ----
    float sm = 0.0f;
    if (xg >= 1 && xg <= 254 && yg >= 1 && yg <= 254) {
        #pragma unroll
        for (int e = 0; e < 4; ++e) {
            int k = k0 + e;
            if (k >= 1 && k <= 61) {
                float dzm = zcv[e + 1] - zcv[e];
                float dzp = zcv[e + 3] - zcv[e + 2];
                float dzw = zWv[e + 1] - zWv[e];
                float dzs = zSv[e + 1] - zSv[e];
                float lap = 6.0f * dz0[e] * dz0[e]
                          - dzw * dzw - dzE[e] * dzE[e]
                          - dzs * dzs - dzN[e] * dzN[e]
                          - dzm * dzm - dzp * dzp;
                sm += lap * lap;
            }
        }
    }

    __syncthreads();   // staging complete

    // ---- div: z corner diffs, then per-field accumulation from LDS ----
    float dv = 0.0f;
    if (xg < 255 && yg < 255) {
        float dCE[5], dCN[5], dENE[5], dNNE[5];
        #pragma unroll
        for (int j = 0; j < 5; ++j) {
            dCE[j]  = zcv[j + 1] - zEv[j];
            dCN[j]  = zcv[j + 1] - zNv[j];
            dENE[j] = zEv[j] - zNEv[j];
            dNNE[j] = zNv[j] - zNEv[j];
        }
        float adz00[4], adz10[4], adz01[4], adz11[4];
        #pragma unroll
        for (int e = 0; e < 4; ++e) {
            adz00[e] = fabsf(dz0[e]);  adz10[e] = fabsf(dzE[e]);
            adz01[e] = fabsf(dzN[e]);  adz11[e] = fabsf(dzNE[e]);
        }

        const float* bxP = &bs[cx * BSTR + cy * 64 + k0];
        const float* byP = bxP + BFLD;
        const float* bzP = byP + BFLD;
        const float c6 = 1.0f / 6.0f;

        float num[4], den[4];

        // -- bx --
        {
            float a00[5], a10[5], a01[5], a11[5];
            ld5(a00, bxP, d4);            ld5(a10, bxP + BSTR, d4);
            ld5(a01, bxP + 64, d4);       ld5(a11, bxP + BSTR + 64, d4);
            #pragma unroll
            for (int e = 0; e < 4; ++e) {
                float s10 = a10[e] + a10[e + 1] + a11[e] + a11[e + 1];
                float s00 = a00[e] + a00[e + 1] + a01[e] + a01[e + 1];
                num[e] = 0.125f * (s10 * (adz10[e] + adz11[e])
                                 - s00 * (adz00[e] + adz01[e]));
                num[e] += c6 * ( (a00[e + 1] + a10[e + 1] + a11[e + 1]) * dCE[e + 1]
                               + (a01[e + 1] + a11[e + 1] + a10[e + 1]) * dNNE[e + 1]
                               - (a00[e] + a10[e] + a11[e]) * dCE[e]
                               - (a01[e] + a11[e] + a10[e]) * dNNE[e] );
                float sbx = s10 + s00;
                den[e] = sbx * sbx;
            }
        }
        // -- by --
        {
            float a00[5], a10[5], a01[5], a11[5];
            ld5(a00, byP, d4);            ld5(a10, byP + BSTR, d4);
            ld5(a01, byP + 64, d4);       ld5(a11, byP + BSTR + 64, d4);
            #pragma unroll
            for (int e = 0; e < 4; ++e) {
                float s01 = a01[e] + a01[e + 1] + a11[e] + a11[e + 1];
                float s00 = a00[e] + a00[e + 1] + a10[e] + a10[e + 1];
                num[e] += 0.125f * (s01 * (adz01[e] + adz11[e])
                                  - s00 * (adz00[e] + adz10[e]));
                num[e] += c6 * ( (a10[e + 1] + a11[e + 1] + a01[e + 1]) * dENE[e + 1]
                               + (a00[e + 1] + a01[e + 1] + a11[e + 1]) * dCN[e + 1]
                               - (a10[e] + a11[e] + a01[e]) * dENE[e]
                               - (a00[e] + a01[e] + a11[e]) * dCN[e] );
                float sby = s01 + s00;
                den[e] += sby * sby;
            }
        }
        // -- bz --
        {
            float a00[5], a10[5], a01[5], a11[5];
            ld5(a00, bzP, d4);            ld5(a10, bzP + BSTR, d4);
            ld5(a01, bzP + 64, d4);       ld5(a11, bzP + BSTR + 64, d4);
            #pragma unroll
            for (int e = 0; e < 4; ++e) {
                float slo = a00[e] + a10[e] + a01[e] + a11[e];
                float shi = a00[e + 1] + a10[e + 1] + a01[e + 1] + a11[e + 1];
                num[e] += 0.25f * (shi - slo);
                float sbz = slo + shi;
                den[e] += sbz * sbz;
            }
        }
        #pragma unroll
        for (int e = 0; e < 4; ++e) {
            if ((k0 + e) < 63) {
                float d = den[e] * 0.015625f + 1e-10f;
                dv += num[e] * num[e] * __builtin_amdgcn_rcpf(d);
            }
        }
    }

    // ---- block reduction (reuse bs as scratch) ----
    #pragma unroll
    for (int off = 32; off > 0; off >>= 1) {
        sm += __shfl_down(sm, off, 64);
        dv += __shfl_down(dv, off, 64);
    }

    __syncthreads();   // all LDS b-reads done; safe to reuse bs
    float* r1 = bs;            // 1024 floats
    float* r2 = bs + 1024;     // 1024 floats
    { float4 v; v.x = s1a[0]; v.y = s1a[1]; v.z = s1a[2]; v.w = s1a[3];
      *(float4*)&r1[tid << 2] = v; }
    { float4 v; v.x = s2a[0]; v.y = s2a[1]; v.z = s2a[2]; v.w = s2a[3];
      *(float4*)&r2[tid << 2] = v; }
    if (lane == 0) { rsc[w][0] = sm; rsc[w][1] = dv; }
    __syncthreads();

    if (tid < 64) {
        float a = 0.0f, b2 = 0.0f;
        #pragma unroll
        for (int cc = 0; cc < 16; ++cc) {
            a  += r1[cc * 64 + tid];
            b2 += r2[cc * 64 + tid];
        }
        float* sl = ws + (blockIdx.x & 31) * 258;
        if (tid < 63) {
            atomicAdd(&sl[2 + bb * 64 + tid],   a);
            atomicAdd(&sl[130 + bb * 64 + tid], b2);
        }
        if (tid == 0) atomicAdd(&sl[0], rsc[0][0] + rsc[1][0] + rsc[2][0] + rsc[3][0]);
        if (tid == 1) atomicAdd(&sl[1], rsc[0][1] + rsc[1][1] + rsc[2][1] + rsc[3][1]);
    }
}

__global__ __launch_bounds__(128) void finalize_kernel(const float* __restrict__ ws,
                                                       float* __restrict__ out)
{
    __shared__ double red[128];
    const int t = threadIdx.x;
    double stdv = 0.0;
    {
        int k = t & 63, bb = t >> 6;
        if (k < 63) {
            double s1 = 0.0, s2 = 0.0;
            for (int p = 0; p < 32; ++p) {
                s1 += (double)ws[p * 258 + 2 + bb * 64 + k];
                s2 += (double)ws[p * 258 + 130 + bb * 64 + k];
            }
            const double N = 65536.0;
            double var = (s2 - s1 * s1 / N) / (N - 1.0);
            stdv = sqrt(var > 0.0 ? var : 0.0);
        }
    }
    red[t] = stdv;
    __syncthreads();
    for (int off = 64; off > 0; off >>= 1) {
        if (t < off) red[t] += red[t + off];
        __syncthreads();
    }
    if (t == 0) {
        double smt = 0.0, dvt = 0.0;
        for (int p = 0; p < 32; ++p) {
            smt += (double)ws[p * 258 + 0];
            dvt += (double)ws[p * 258 + 1];
        }
        double loss_std    = red[0] / 126.0;
        double loss_smooth = smt / (2.0 * 254.0 * 254.0 * 61.0);
        double loss_div    = dvt / (2.0 * 255.0 * 255.0 * 63.0);
        out[0] = (float)(loss_div * 1e9);
        out[1] = (float)(loss_smooth * 10.0 + loss_std * 100.0);
    }
}

extern "C" void kernel_launch(void* const* d_in, const int* in_sizes, int n_in,
                              void* d_out, int out_size, void* d_ws, size_t ws_size,
                              hipStream_t stream) {
    const float* z  = (const float*)d_in[0];   // outputs (2,1,256,256,64)
    const float* tg = (const float*)d_in[1];   // targets (2,3,256,256,64)
    float* out = (float*)d_out;
    float* ws  = (float*)d_ws;

    zero_ws_kernel<<<1, 512, 0, stream>>>(ws);
    // 64x64 tiles x 2 batches = 8192 blocks
    fused_loss_kernel<<<8192, 256, 0, stream>>>(z, tg, ws);
    finalize_kernel<<<1, 128, 0, stream>>>(ws, out);
}